// Round 1
// 249.781 us; speedup vs baseline: 1.0622x; 1.0622x over previous
//
#include <hip/hip_runtime.h>
#include <hip/hip_bf16.h>
#include <stdint.h>

// Problem constants (b=16, l=4096, d=256, c=256, qk_dim=256, heads=8)
// Inputs: float32. Outputs: FLOAT32:
//   out[0..65536)       k  [8,256,32]
//   out[65536..131072)  v  [8,256,32]
//   out[131072..196608) x_global [256,256]
#define DD 256
#define CC 256

typedef __attribute__((ext_vector_type(8))) short bf16x8;
typedef __attribute__((ext_vector_type(4))) float f32x4;

// round-to-nearest-even f32 -> bf16; also returns the rounded value as f32
__device__ __forceinline__ unsigned short bf16_rn(float v, float& hval) {
    unsigned u = __builtin_bit_cast(unsigned, v);
    unsigned r = u + 0x7FFFu + ((u >> 16) & 1u);
    hval = __builtin_bit_cast(float, r & 0xFFFF0000u);
    return (unsigned short)(r >> 16);
}

// ---------------------------------------------------------------------------
// K1: normalize cluster means (f32); emit split-bf16 packed per 64-cluster
// GROUP for the barrier-free assign kernel:
//   mpk2[g(4)][ hi: [kc(8)][q(4)][ct(4)][m(16)][8] | lo: same ]  (64KB/group)
// cluster c = g*64 + ct*16 + m ; dim d = kc*32 + q*8 + j.
// Also zero sums + bins + pk (packed argmax cells).
__global__ __launch_bounds__(256) void k_prep(const float* __restrict__ xm,
                                              float* __restrict__ means_n,
                                              unsigned short* __restrict__ mpk2,
                                              unsigned long long* __restrict__ pk,
                                              float* __restrict__ sums,
                                              int* __restrict__ bins) {
    __shared__ float red[256];
    int c = blockIdx.x, t = threadIdx.x;
    float v = xm[c * DD + t];
    red[t] = v * v;
    __syncthreads();
    for (int off = 128; off > 0; off >>= 1) {
        if (t < off) red[t] += red[t + off];
        __syncthreads();
    }
    float inv = 1.0f / fmaxf(sqrtf(red[0]), 1e-12f);
    float vn = v * inv;
    means_n[c * DD + t] = vn;
    float hf; unsigned short hb = bf16_rn(vn, hf);
    float lo = vn - hf;                 // exact
    float d2; unsigned short lb = bf16_rn(lo, d2);
    int g = c >> 6, ct = (c >> 4) & 3, m = c & 15;
    int kc = t >> 5, q = (t >> 3) & 3, j = t & 7;
    size_t base = (size_t)g * 32768 + ((kc * 4 + q) * 64 + ct * 16 + m) * 8 + j;
    mpk2[base]         = hb;            // hi half
    mpk2[base + 16384] = lb;            // lo half
    sums[c * DD + t] = 0.0f;
    pk[c * 256 + t] = 0ull;             // 0 == -NaN sentinel, below all reals
    if (c == 0) bins[t] = 0;
}

// ---------------------------------------------------------------------------
// K2 v6: BARRIER-FREE MFMA similarity (cluster-split) + packed-atomicMax argmax.
// R9 lesson: every double-buffer variant pinned at ~96us / MfmaUtil 10% --
// the kc-loop barrier convoy (8 waves x 8 barriers, x-prefetch drained in
// vmcnt(0), only 2 blocks/CU) was the invariant. v6 removes the barrier:
// block = 8 waves, stages 64 clusters x full K (hi+lo = exactly 64KB LDS)
// ONCE, then waves free-run. Wave owns 32 points (2 A-tiles): acc = 32 AGPR,
// ~100 unified regs -> 4 waves/SIMD, 2 blocks/CU = 16 waves. grid.y = 4
// cluster-groups; partial winners merged via u64 atomicMax of
// (orderable(val)<<32)|(255-cluster)  => max val, tie -> lowest cluster.
// 3-MFMA split-bf16 (hh+lh+hl): dists bit-identical to R5-R9.
// C/D layout: cluster_in_group=ct*16+(lane&15), point=tile_p0+q*4+reg.
__global__ __launch_bounds__(512, 4) void k_assign(
        const float* __restrict__ x,
        const unsigned short* __restrict__ mpk2,
        unsigned long long* __restrict__ pk,
        float* __restrict__ inv_norm) {
    __shared__ __align__(16) unsigned short mlds[32768];   // 64KB
    int t = threadIdx.x;
    int w = t >> 6, lane = t & 63;             // w in 0..7
    int m = lane & 15, q = lane >> 4;          // q in 0..3
    int g = blockIdx.y;                        // cluster group (64 clusters)
    int p0 = blockIdx.x * 256 + w * 32;
    const float* xq0 = x + (size_t)(p0 + m) * DD + q * 8;
    const float* xq1 = xq0 + 16 * DD;

    // one-time stage: 64KB, 8 instr/thread, wave-uniform LDS base (16B/lane)
    {
        const unsigned short* gsrc = mpk2 + (size_t)g * 32768 + w * 4096 + lane * 8;
        unsigned short* lb = mlds + w * 4096;
#pragma unroll
        for (int i = 0; i < 8; i++)
            __builtin_amdgcn_global_load_lds(
                (const __attribute__((address_space(1))) void*)(gsrc + i * 512),
                (__attribute__((address_space(3))) void*)(lb + i * 512),
                16, 0, 0);
    }
    __syncthreads();   // the ONLY barrier

    f32x4 acc0[4], acc1[4];
#pragma unroll
    for (int ct = 0; ct < 4; ct++) {
        acc0[ct] = (f32x4){0.f, 0.f, 0.f, 0.f};
        acc1[ct] = (f32x4){0.f, 0.f, 0.f, 0.f};
    }
    float ss0 = 0.f, ss1 = 0.f;

#pragma unroll 2
    for (int kc = 0; kc < 8; kc++) {
        float4 xa0 = *(const float4*)(xq0 + kc * 32);
        float4 xb0 = *(const float4*)(xq0 + kc * 32 + 4);
        float4 xa1 = *(const float4*)(xq1 + kc * 32);
        float4 xb1 = *(const float4*)(xq1 + kc * 32 + 4);
        ss0 += xa0.x * xa0.x + xa0.y * xa0.y + xa0.z * xa0.z + xa0.w * xa0.w +
               xb0.x * xb0.x + xb0.y * xb0.y + xb0.z * xb0.z + xb0.w * xb0.w;
        ss1 += xa1.x * xa1.x + xa1.y * xa1.y + xa1.z * xa1.z + xa1.w * xa1.w +
               xb1.x * xb1.x + xb1.y * xb1.y + xb1.z * xb1.z + xb1.w * xb1.w;
        float xv0[8] = {xa0.x, xa0.y, xa0.z, xa0.w, xb0.x, xb0.y, xb0.z, xb0.w};
        float xv1[8] = {xa1.x, xa1.y, xa1.z, xa1.w, xb1.x, xb1.y, xb1.z, xb1.w};
        bf16x8 ah0, al0, ah1, al1;
#pragma unroll
        for (int j = 0; j < 8; j++) {
            float hf; unsigned short hb = bf16_rn(xv0[j], hf);
            float lo = xv0[j] - hf; float d2;
            al0[j] = (short)bf16_rn(lo, d2); ah0[j] = (short)hb;
            hb = bf16_rn(xv1[j], hf);
            lo = xv1[j] - hf;
            al1[j] = (short)bf16_rn(lo, d2); ah1[j] = (short)hb;
        }

        const unsigned short* fb = mlds + (kc * 4 + q) * 512 + m * 8;
#pragma unroll
        for (int ct = 0; ct < 4; ct++) {
            bf16x8 bh = *(const bf16x8*)(fb + ct * 128);
            bf16x8 bl = *(const bf16x8*)(fb + 16384 + ct * 128);
            acc0[ct] = __builtin_amdgcn_mfma_f32_16x16x32_bf16(ah0, bh, acc0[ct], 0, 0, 0);
            acc0[ct] = __builtin_amdgcn_mfma_f32_16x16x32_bf16(al0, bh, acc0[ct], 0, 0, 0);
            acc0[ct] = __builtin_amdgcn_mfma_f32_16x16x32_bf16(ah0, bl, acc0[ct], 0, 0, 0);
            acc1[ct] = __builtin_amdgcn_mfma_f32_16x16x32_bf16(ah1, bh, acc1[ct], 0, 0, 0);
            acc1[ct] = __builtin_amdgcn_mfma_f32_16x16x32_bf16(al1, bh, acc1[ct], 0, 0, 0);
            acc1[ct] = __builtin_amdgcn_mfma_f32_16x16x32_bf16(ah1, bl, acc1[ct], 0, 0, 0);
        }
    }

    // row inv-norms (only group 0 computes/writes them)
    if (g == 0) {
        ss0 += __shfl_xor(ss0, 16, 64); ss0 += __shfl_xor(ss0, 32, 64);
        ss1 += __shfl_xor(ss1, 16, 64); ss1 += __shfl_xor(ss1, 32, 64);
        if (q == 0) {
            inv_norm[p0 + m]      = 1.0f / fmaxf(sqrtf(ss0), 1e-12f);
            inv_norm[p0 + 16 + m] = 1.0f / fmaxf(sqrtf(ss1), 1e-12f);
        }
    }

    // per-lane argmax over ascending ct (strict > keeps lowest cluster)
    float bv0[4], bv1[4]; int bi0[4], bi1[4];
#pragma unroll
    for (int r = 0; r < 4; r++) {
        bv0[r] = acc0[0][r]; bi0[r] = m;
        bv1[r] = acc1[0][r]; bi1[r] = m;
#pragma unroll
        for (int ct = 1; ct < 4; ct++) {
            float v2 = acc0[ct][r];
            if (v2 > bv0[r]) { bv0[r] = v2; bi0[r] = ct * 16 + m; }
            float v3 = acc1[ct][r];
            if (v3 > bv1[r]) { bv1[r] = v3; bi1[r] = ct * 16 + m; }
        }
    }
    // reduce across the 16 m-lanes; tie -> lowest cluster index
#pragma unroll
    for (int mask = 1; mask < 16; mask <<= 1) {
#pragma unroll
        for (int r = 0; r < 4; r++) {
            float ov = __shfl_xor(bv0[r], mask, 64);
            int   oi = __shfl_xor(bi0[r], mask, 64);
            if (ov > bv0[r] || (ov == bv0[r] && oi < bi0[r])) { bv0[r] = ov; bi0[r] = oi; }
            ov = __shfl_xor(bv1[r], mask, 64);
            oi = __shfl_xor(bi1[r], mask, 64);
            if (ov > bv1[r] || (ov == bv1[r] && oi < bi1[r])) { bv1[r] = ov; bi1[r] = oi; }
        }
    }
    if (m == 0) {
#pragma unroll
        for (int r = 0; r < 4; r++) {
            // pack: orderable float in high 32, (255 - cluster) low => max val,
            // ties -> lowest global cluster index (first-occurrence semantics)
            unsigned ub0 = __builtin_bit_cast(unsigned, bv0[r]);
            ub0 = (ub0 & 0x80000000u) ? ~ub0 : (ub0 | 0x80000000u);
            unsigned long long pv0 = ((unsigned long long)ub0 << 32)
                                   | (unsigned)(255 - (g * 64 + bi0[r]));
            atomicMax(&pk[p0 + q * 4 + r], pv0);
            unsigned ub1 = __builtin_bit_cast(unsigned, bv1[r]);
            ub1 = (ub1 & 0x80000000u) ? ~ub1 : (ub1 | 0x80000000u);
            unsigned long long pv1 = ((unsigned long long)ub1 << 32)
                                   | (unsigned)(255 - (g * 64 + bi1[r]));
            atomicMax(&pk[p0 + 16 + q * 4 + r], pv1);
        }
    }
}

// ---------------------------------------------------------------------------
// K3 v4: scatter-add of normalized x into sums. Decodes buckets from pk.
// R10: global f32 atomicAdd on MI355X is a memory-side RMW -- WRITE_SIZE
// showed 65.8MB = 16.7M atomics x 4B all hitting HBM; the flush dominated
// (117us at 10% HBM BW, VALUBusy 4.6%). Amortize: 1024 points per block
// (PC=1024), grid (64,8) = 512 blocks -> flush atomics drop 4x to 4.2M.
// LDS 41KB (slab 32K + lb 4K + lw 4K + hist 1K) -> still 3 blocks/CU.
// buckets+inv_norm preloaded to LDS; unroll-16 load batches for MLP.
// blockIdx.y==0 blocks also accumulate bins (histogram) for k_xgkv.
#define PC 1024
__global__ __launch_bounds__(256) void k_scatter(const float* __restrict__ x,
                                                 const unsigned long long* __restrict__ pk,
                                                 const float* __restrict__ inv_norm,
                                                 float* __restrict__ sums,
                                                 int* __restrict__ bins) {
    __shared__ float acc[256 * 32];   // 32KB slab [cluster][coord]
    __shared__ int   lb[PC];
    __shared__ float lw[PC];
    __shared__ int   hist[256];
    int t = threadIdx.x;
    for (int i = t; i < 8192; i += 256) acc[i] = 0.0f;
    hist[t] = 0;
    int n0 = blockIdx.x * PC;
    // decode this chunk's buckets + load inv_norm (coalesced)
#pragma unroll
    for (int i = t; i < PC; i += 256) {
        unsigned long long v = pk[n0 + i];
        lb[i] = 255 - (int)(v & 0xFFu);   // low 32 bits = 255 - cluster
        lw[i] = inv_norm[n0 + i];
    }
    __syncthreads();
    if (blockIdx.y == 0) {                     // LDS histogram
#pragma unroll
        for (int i = t; i < PC; i += 256) atomicAdd(&hist[lb[i]], 1);
    }
    int co = t & 31, pg = t >> 5;               // 8 point-groups
    int c0 = blockIdx.y * 32;
    const float* xb = x + (size_t)n0 * DD + c0 + co;
    for (int i = 0; i < PC / 8; i += 16) {
        float v[16]; int bb[16];
#pragma unroll
        for (int j = 0; j < 16; j++) {
            int p = (i + j) * 8 + pg;           // point within chunk
            v[j]  = xb[(size_t)p * DD] * lw[p];
            bb[j] = lb[p];
        }
#pragma unroll
        for (int j = 0; j < 16; j++) atomicAdd(&acc[bb[j] * 32 + co], v[j]);
    }
    __syncthreads();
    for (int k2 = 0; k2 < 32; k2++) {
        int flat = k2 * 256 + t;
        atomicAdd(&sums[(flat >> 5) * DD + c0 + (flat & 31)], acc[flat]);
    }
    if (blockIdx.y == 0 && hist[t] > 0) atomicAdd(&bins[t], hist[t]);
}

// ---------------------------------------------------------------------------
// K4+K5 fused: x_global = l2norm(sums) (or old mean if empty bin), then
// k = xg @ Wk^T, v = xg @ Wv^T in [h][c][dh] layout. All f32. 256 blocks.
__global__ __launch_bounds__(256) void k_xgkv(const float* __restrict__ sums,
                                              const int* __restrict__ bins,
                                              const float* __restrict__ means_n,
                                              const float* __restrict__ Wk,
                                              const float* __restrict__ Wv,
                                              float* __restrict__ out) {
    __shared__ float red[256];
    __shared__ __align__(16) float xr[256];
    int c = blockIdx.x, t = threadIdx.x;
    float s = sums[c * DD + t];
    red[t] = s * s;
    __syncthreads();
    for (int off = 128; off > 0; off >>= 1) {
        if (t < off) red[t] += red[t + off];
        __syncthreads();
    }
    float g;
    if (bins[c] > 0) g = s / fmaxf(sqrtf(red[0]), 1e-12f);
    else             g = means_n[c * DD + t];
    out[131072 + c * DD + t] = g;   // output 2: x_global
    xr[t] = g;
    __syncthreads();

    float ak = 0.f, av = 0.f;
    const float4* wkp = (const float4*)(Wk + (size_t)t * DD);
    const float4* wvp = (const float4*)(Wv + (size_t)t * DD);
#pragma unroll 8
    for (int j4 = 0; j4 < 64; j4++) {
        float4 wk = wkp[j4], wv = wvp[j4];
        float4 a = *(const float4*)(xr + j4 * 4);
        ak += a.x * wk.x + a.y * wk.y + a.z * wk.z + a.w * wk.w;
        av += a.x * wv.x + a.y * wv.y + a.z * wv.z + a.w * wv.w;
    }
    int h = t >> 5, dh = t & 31;
    out[h * 8192 + c * 32 + dh]         = ak;   // output 0: k
    out[65536 + h * 8192 + c * 32 + dh] = av;   // output 1: v
}

// ---------------------------------------------------------------------------
extern "C" void kernel_launch(void* const* d_in, const int* in_sizes, int n_in,
                              void* d_out, int out_size, void* d_ws, size_t ws_size,
                              hipStream_t stream) {
    (void)in_sizes; (void)n_in; (void)out_size; (void)ws_size;
    const float* x  = (const float*)d_in[0];  // [16,4096,256] f32
    const float* xm = (const float*)d_in[1];  // [256,256] f32
    const float* Wk = (const float*)d_in[2];  // [256,256] f32
    const float* Wv = (const float*)d_in[3];  // [256,256] f32

    float* ws       = (float*)d_ws;
    float* means_n  = ws;                                      // 65536 f32
    float* inv_norm = ws + 65536;                              // 65536 f32
    unsigned long long* pk = (unsigned long long*)(ws + 131072); // 65536 u64
    float* sums     = ws + 262144;                             // 65536 f32
    int*   bins     = (int*)(ws + 327680);                     // 256 int
    unsigned short* mpk2 = (unsigned short*)(ws + 327936);     // 131072 bf16
    float* out      = (float*)d_out;

    k_prep   <<<256, 256, 0, stream>>>(xm, means_n, mpk2, pk, sums, bins);
    k_assign <<<dim3(256, 4), 512, 0, stream>>>(x, mpk2, pk, inv_norm);
    k_scatter<<<dim3(64, 8), 256, 0, stream>>>(x, pk, inv_norm, sums, bins);
    k_xgkv   <<<256, 256, 0, stream>>>(sums, bins, means_n, Wk, Wv, out);
}

// Round 2
// 172.358 us; speedup vs baseline: 1.5394x; 1.4492x over previous
//
#include <hip/hip_runtime.h>
#include <hip/hip_bf16.h>
#include <stdint.h>

// Problem constants (b=16, l=4096, d=256, c=256, qk_dim=256, heads=8)
// Inputs: float32. Outputs: FLOAT32:
//   out[0..65536)       k  [8,256,32]
//   out[65536..131072)  v  [8,256,32]
//   out[131072..196608) x_global [256,256]
#define DD 256
#define CC 256
#define MAXN 1024   // per-cluster list slab (mean 256, std ~16; 1024 is >40 sigma)

typedef __attribute__((ext_vector_type(8))) short bf16x8;
typedef __attribute__((ext_vector_type(4))) float f32x4;

// round-to-nearest-even f32 -> bf16; also returns the rounded value as f32
__device__ __forceinline__ unsigned short bf16_rn(float v, float& hval) {
    unsigned u = __builtin_bit_cast(unsigned, v);
    unsigned r = u + 0x7FFFu + ((u >> 16) & 1u);
    hval = __builtin_bit_cast(float, r & 0xFFFF0000u);
    return (unsigned short)(r >> 16);
}

// ---------------------------------------------------------------------------
// K1: normalize cluster means (f32); emit split-bf16 packed per 64-cluster
// GROUP for the barrier-free assign kernel:
//   mpk2[g(4)][ hi: [kc(8)][q(4)][ct(4)][m(16)][8] | lo: same ]  (64KB/group)
// cluster c = g*64 + ct*16 + m ; dim d = kc*32 + q*8 + j.
// Also zero pk (packed argmax cells) + bins.
__global__ __launch_bounds__(256) void k_prep(const float* __restrict__ xm,
                                              float* __restrict__ means_n,
                                              unsigned short* __restrict__ mpk2,
                                              unsigned long long* __restrict__ pk,
                                              int* __restrict__ bins) {
    __shared__ float red[256];
    int c = blockIdx.x, t = threadIdx.x;
    float v = xm[c * DD + t];
    red[t] = v * v;
    __syncthreads();
    for (int off = 128; off > 0; off >>= 1) {
        if (t < off) red[t] += red[t + off];
        __syncthreads();
    }
    float inv = 1.0f / fmaxf(sqrtf(red[0]), 1e-12f);
    float vn = v * inv;
    means_n[c * DD + t] = vn;
    float hf; unsigned short hb = bf16_rn(vn, hf);
    float lo = vn - hf;                 // exact
    float d2; unsigned short lb = bf16_rn(lo, d2);
    int g = c >> 6, ct = (c >> 4) & 3, m = c & 15;
    int kc = t >> 5, q = (t >> 3) & 3, j = t & 7;
    size_t base = (size_t)g * 32768 + ((kc * 4 + q) * 64 + ct * 16 + m) * 8 + j;
    mpk2[base]         = hb;            // hi half
    mpk2[base + 16384] = lb;            // lo half
    pk[c * 256 + t] = 0ull;             // 0 == -NaN sentinel, below all reals
    if (c == 0) bins[t] = 0;
}

// ---------------------------------------------------------------------------
// K2 v6: BARRIER-FREE MFMA similarity (cluster-split) + packed-atomicMax argmax.
// (unchanged from R1; next round's fusion target -- it re-reads x 4x via grid.y)
__global__ __launch_bounds__(512, 4) void k_assign(
        const float* __restrict__ x,
        const unsigned short* __restrict__ mpk2,
        unsigned long long* __restrict__ pk,
        float* __restrict__ inv_norm) {
    __shared__ __align__(16) unsigned short mlds[32768];   // 64KB
    int t = threadIdx.x;
    int w = t >> 6, lane = t & 63;             // w in 0..7
    int m = lane & 15, q = lane >> 4;          // q in 0..3
    int g = blockIdx.y;                        // cluster group (64 clusters)
    int p0 = blockIdx.x * 256 + w * 32;
    const float* xq0 = x + (size_t)(p0 + m) * DD + q * 8;
    const float* xq1 = xq0 + 16 * DD;

    // one-time stage: 64KB, 8 instr/thread, wave-uniform LDS base (16B/lane)
    {
        const unsigned short* gsrc = mpk2 + (size_t)g * 32768 + w * 4096 + lane * 8;
        unsigned short* lb = mlds + w * 4096;
#pragma unroll
        for (int i = 0; i < 8; i++)
            __builtin_amdgcn_global_load_lds(
                (const __attribute__((address_space(1))) void*)(gsrc + i * 512),
                (__attribute__((address_space(3))) void*)(lb + i * 512),
                16, 0, 0);
    }
    __syncthreads();   // the ONLY barrier

    f32x4 acc0[4], acc1[4];
#pragma unroll
    for (int ct = 0; ct < 4; ct++) {
        acc0[ct] = (f32x4){0.f, 0.f, 0.f, 0.f};
        acc1[ct] = (f32x4){0.f, 0.f, 0.f, 0.f};
    }
    float ss0 = 0.f, ss1 = 0.f;

#pragma unroll 2
    for (int kc = 0; kc < 8; kc++) {
        float4 xa0 = *(const float4*)(xq0 + kc * 32);
        float4 xb0 = *(const float4*)(xq0 + kc * 32 + 4);
        float4 xa1 = *(const float4*)(xq1 + kc * 32);
        float4 xb1 = *(const float4*)(xq1 + kc * 32 + 4);
        ss0 += xa0.x * xa0.x + xa0.y * xa0.y + xa0.z * xa0.z + xa0.w * xa0.w +
               xb0.x * xb0.x + xb0.y * xb0.y + xb0.z * xb0.z + xb0.w * xb0.w;
        ss1 += xa1.x * xa1.x + xa1.y * xa1.y + xa1.z * xa1.z + xa1.w * xa1.w +
               xb1.x * xb1.x + xb1.y * xb1.y + xb1.z * xb1.z + xb1.w * xb1.w;
        float xv0[8] = {xa0.x, xa0.y, xa0.z, xa0.w, xb0.x, xb0.y, xb0.z, xb0.w};
        float xv1[8] = {xa1.x, xa1.y, xa1.z, xa1.w, xb1.x, xb1.y, xb1.z, xb1.w};
        bf16x8 ah0, al0, ah1, al1;
#pragma unroll
        for (int j = 0; j < 8; j++) {
            float hf; unsigned short hb = bf16_rn(xv0[j], hf);
            float lo = xv0[j] - hf; float d2;
            al0[j] = (short)bf16_rn(lo, d2); ah0[j] = (short)hb;
            hb = bf16_rn(xv1[j], hf);
            lo = xv1[j] - hf;
            al1[j] = (short)bf16_rn(lo, d2); ah1[j] = (short)hb;
        }

        const unsigned short* fb = mlds + (kc * 4 + q) * 512 + m * 8;
#pragma unroll
        for (int ct = 0; ct < 4; ct++) {
            bf16x8 bh = *(const bf16x8*)(fb + ct * 128);
            bf16x8 bl = *(const bf16x8*)(fb + 16384 + ct * 128);
            acc0[ct] = __builtin_amdgcn_mfma_f32_16x16x32_bf16(ah0, bh, acc0[ct], 0, 0, 0);
            acc0[ct] = __builtin_amdgcn_mfma_f32_16x16x32_bf16(al0, bh, acc0[ct], 0, 0, 0);
            acc0[ct] = __builtin_amdgcn_mfma_f32_16x16x32_bf16(ah0, bl, acc0[ct], 0, 0, 0);
            acc1[ct] = __builtin_amdgcn_mfma_f32_16x16x32_bf16(ah1, bh, acc1[ct], 0, 0, 0);
            acc1[ct] = __builtin_amdgcn_mfma_f32_16x16x32_bf16(al1, bh, acc1[ct], 0, 0, 0);
            acc1[ct] = __builtin_amdgcn_mfma_f32_16x16x32_bf16(ah1, bl, acc1[ct], 0, 0, 0);
        }
    }

    // row inv-norms (only group 0 computes/writes them)
    if (g == 0) {
        ss0 += __shfl_xor(ss0, 16, 64); ss0 += __shfl_xor(ss0, 32, 64);
        ss1 += __shfl_xor(ss1, 16, 64); ss1 += __shfl_xor(ss1, 32, 64);
        if (q == 0) {
            inv_norm[p0 + m]      = 1.0f / fmaxf(sqrtf(ss0), 1e-12f);
            inv_norm[p0 + 16 + m] = 1.0f / fmaxf(sqrtf(ss1), 1e-12f);
        }
    }

    // per-lane argmax over ascending ct (strict > keeps lowest cluster)
    float bv0[4], bv1[4]; int bi0[4], bi1[4];
#pragma unroll
    for (int r = 0; r < 4; r++) {
        bv0[r] = acc0[0][r]; bi0[r] = m;
        bv1[r] = acc1[0][r]; bi1[r] = m;
#pragma unroll
        for (int ct = 1; ct < 4; ct++) {
            float v2 = acc0[ct][r];
            if (v2 > bv0[r]) { bv0[r] = v2; bi0[r] = ct * 16 + m; }
            float v3 = acc1[ct][r];
            if (v3 > bv1[r]) { bv1[r] = v3; bi1[r] = ct * 16 + m; }
        }
    }
    // reduce across the 16 m-lanes; tie -> lowest cluster index
#pragma unroll
    for (int mask = 1; mask < 16; mask <<= 1) {
#pragma unroll
        for (int r = 0; r < 4; r++) {
            float ov = __shfl_xor(bv0[r], mask, 64);
            int   oi = __shfl_xor(bi0[r], mask, 64);
            if (ov > bv0[r] || (ov == bv0[r] && oi < bi0[r])) { bv0[r] = ov; bi0[r] = oi; }
            ov = __shfl_xor(bv1[r], mask, 64);
            oi = __shfl_xor(bi1[r], mask, 64);
            if (ov > bv1[r] || (ov == bv1[r] && oi < bi1[r])) { bv1[r] = ov; bi1[r] = oi; }
        }
    }
    if (m == 0) {
#pragma unroll
        for (int r = 0; r < 4; r++) {
            // pack: orderable float in high 32, (255 - cluster) low => max val,
            // ties -> lowest global cluster index (first-occurrence semantics)
            unsigned ub0 = __builtin_bit_cast(unsigned, bv0[r]);
            ub0 = (ub0 & 0x80000000u) ? ~ub0 : (ub0 | 0x80000000u);
            unsigned long long pv0 = ((unsigned long long)ub0 << 32)
                                   | (unsigned)(255 - (g * 64 + bi0[r]));
            atomicMax(&pk[p0 + q * 4 + r], pv0);
            unsigned ub1 = __builtin_bit_cast(unsigned, bv1[r]);
            ub1 = (ub1 & 0x80000000u) ? ~ub1 : (ub1 | 0x80000000u);
            unsigned long long pv1 = ((unsigned long long)ub1 << 32)
                                   | (unsigned)(255 - (g * 64 + bi1[r]));
            atomicMax(&pk[p0 + 16 + q * 4 + r], pv1);
        }
    }
}

// ---------------------------------------------------------------------------
// K3 v5 (R2): the scatter is a permutation -- SORT indices by bucket instead
// of scattering values. R1 post-mortem: slab scatter was latency-serialized
// (16.7M scalar loads + 16.7M LDS atomics at 2 blocks/CU: 97us, 6.5% HBM,
// 3% VALU). k_sort builds per-cluster point lists: LDS hist for local rank,
// ONE global atomicAdd per (block,cluster) for the base (16K atomics total),
// u16 index writes. Stability across blocks is lost -- f32 sum-order noise
// ~1e-6, far under tolerance.
__global__ __launch_bounds__(256) void k_sort(const unsigned long long* __restrict__ pk,
                                              unsigned short* __restrict__ list,
                                              int* __restrict__ bins) {
    __shared__ int hist[256];
    __shared__ int base[256];
    __shared__ unsigned short lpos[1024];
    int t = threadIdx.x;
    hist[t] = 0;
    __syncthreads();
    int p0 = blockIdx.x * 1024;
    int bkt[4];
#pragma unroll
    for (int j = 0; j < 4; j++) {
        int p = p0 + j * 256 + t;
        int b = 255 - (int)(pk[p] & 0xFFu);
        bkt[j] = b;
        lpos[j * 256 + t] = (unsigned short)atomicAdd(&hist[b], 1);
    }
    __syncthreads();
    base[t] = hist[t] > 0 ? atomicAdd(&bins[t], hist[t]) : 0;
    __syncthreads();
#pragma unroll
    for (int j = 0; j < 4; j++) {
        int b = bkt[j];
        int slot = base[b] + (int)lpos[j * 256 + t];
        list[b * MAXN + slot] = (unsigned short)(p0 + j * 256 + t);
    }
}

// ---------------------------------------------------------------------------
// K4 (R2): gather-reduce per cluster + fused l2norm + k/v GEMV (old k_xgkv).
// Block c gathers its cnt (~256) rows of x (each row 1KB, fully coalesced
// across the block), accumulates sums[c][t] in a register, normalizes, and
// immediately computes k/v. No atomics, no sums round-trip, one less launch.
__global__ __launch_bounds__(256) void k_rxgkv(const float* __restrict__ x,
                                               const unsigned short* __restrict__ list,
                                               const int* __restrict__ bins,
                                               const float* __restrict__ inv_norm,
                                               const float* __restrict__ means_n,
                                               const float* __restrict__ Wk,
                                               const float* __restrict__ Wv,
                                               float* __restrict__ out) {
    __shared__ float red[256];
    __shared__ __align__(16) float xr[256];
    __shared__ int   plist[MAXN];
    __shared__ float linv[MAXN];
    int c = blockIdx.x, t = threadIdx.x;
    int cnt = bins[c];
    for (int i = t; i < cnt; i += 256) {
        int p = (int)list[c * MAXN + i];
        plist[i] = p;
        linv[i]  = inv_norm[p];
    }
    __syncthreads();
    float s = 0.f;
    int i = 0;
    // 16-deep load batches: 16 independent gathers in flight per stall window
    for (; i + 16 <= cnt; i += 16) {
        float xv[16], lv[16];
#pragma unroll
        for (int j = 0; j < 16; j++) {
            xv[j] = x[(size_t)plist[i + j] * DD + t];
            lv[j] = linv[i + j];
        }
#pragma unroll
        for (int j = 0; j < 16; j++) s += xv[j] * lv[j];
    }
    for (; i < cnt; i++) s += x[(size_t)plist[i] * DD + t] * linv[i];

    // l2norm(sums) or keep old mean if empty
    red[t] = s * s;
    __syncthreads();
    for (int off = 128; off > 0; off >>= 1) {
        if (t < off) red[t] += red[t + off];
        __syncthreads();
    }
    float g;
    if (cnt > 0) g = s / fmaxf(sqrtf(red[0]), 1e-12f);
    else         g = means_n[c * DD + t];
    out[131072 + c * DD + t] = g;   // output 2: x_global
    xr[t] = g;
    __syncthreads();

    float ak = 0.f, av = 0.f;
    const float4* wkp = (const float4*)(Wk + (size_t)t * DD);
    const float4* wvp = (const float4*)(Wv + (size_t)t * DD);
#pragma unroll 8
    for (int j4 = 0; j4 < 64; j4++) {
        float4 wk = wkp[j4], wv = wvp[j4];
        float4 a = *(const float4*)(xr + j4 * 4);
        ak += a.x * wk.x + a.y * wk.y + a.z * wk.z + a.w * wk.w;
        av += a.x * wv.x + a.y * wv.y + a.z * wv.z + a.w * wv.w;
    }
    int h = t >> 5, dh = t & 31;
    out[h * 8192 + c * 32 + dh]         = ak;   // output 0: k
    out[65536 + h * 8192 + c * 32 + dh] = av;   // output 1: v
}

// ---------------------------------------------------------------------------
extern "C" void kernel_launch(void* const* d_in, const int* in_sizes, int n_in,
                              void* d_out, int out_size, void* d_ws, size_t ws_size,
                              hipStream_t stream) {
    (void)in_sizes; (void)n_in; (void)out_size; (void)ws_size;
    const float* x  = (const float*)d_in[0];  // [16,4096,256] f32
    const float* xm = (const float*)d_in[1];  // [256,256] f32
    const float* Wk = (const float*)d_in[2];  // [256,256] f32
    const float* Wv = (const float*)d_in[3];  // [256,256] f32

    float* ws       = (float*)d_ws;
    float* means_n  = ws;                                        // 65536 f32
    float* inv_norm = ws + 65536;                                // 65536 f32
    unsigned long long* pk = (unsigned long long*)(ws + 131072); // 65536 u64
    int*   bins     = (int*)(ws + 262144);                       // 256 int
    unsigned short* mpk2 = (unsigned short*)(ws + 262400);       // 131072 u16
    unsigned short* list = (unsigned short*)(ws + 327936);       // 262144 u16
    float* out      = (float*)d_out;

    k_prep  <<<256, 256, 0, stream>>>(xm, means_n, mpk2, pk, bins);
    k_assign<<<dim3(256, 4), 512, 0, stream>>>(x, mpk2, pk, inv_norm);
    k_sort  <<<64, 256, 0, stream>>>(pk, list, bins);
    k_rxgkv <<<256, 256, 0, stream>>>(x, list, bins, inv_norm, means_n, Wk, Wv, out);
}